// Round 9
// baseline (1880.173 us; speedup 1.0000x reference)
//
#include <hip/hip_runtime.h>
#include <hip/hip_bf16.h>
#include <stdint.h>

#define HD 4096
#define VD 32000
#define BT 2048        // B*T rows
#define TT 512
#define IGNORE_IDX (-100)

// bf16 8-wave main GEMM geometry
#define BM 256
#define BN 256
#define BKT 64
#define KT (HD / BKT)          // 64 K-tiles
#define NB (VD / BN)           // 125
#define MB (BT / BM)           // 8
#define NWG2 (MB * NB * 2)     // 2000

// partials granularity (64 columns per chunk) — shared with f32 fallback
#define NCHUNK (VD / 64)       // 500

typedef __attribute__((ext_vector_type(8))) short short8;
typedef __attribute__((ext_vector_type(4))) float f32x4;

__device__ __forceinline__ uint16_t f2bf(float f) {
    uint32_t u = __float_as_uint(f);
    u += 0x7FFFu + ((u >> 16) & 1u);   // round-to-nearest-even
    return (uint16_t)(u >> 16);
}

__device__ __forceinline__ void gload16(const void* g, void* l) {
    __builtin_amdgcn_global_load_lds(
        (const __attribute__((address_space(1))) void*)g,
        (__attribute__((address_space(3))) void*)l, 16, 0, 0);
}

#define SBAR __builtin_amdgcn_sched_barrier(0)

// ---------------- kernel 0a: convert x inputs f32 -> bf16 ----------------
__global__ void convert_x(const float* __restrict__ x0, const float* __restrict__ x1,
                          uint16_t* __restrict__ xbf) {
    const int64_t n4 = (int64_t)BT * HD / 4;
    ushort4* o0 = (ushort4*)xbf;
    ushort4* o1 = (ushort4*)(xbf + (int64_t)BT * HD);
    for (int64_t i = blockIdx.x * (int64_t)blockDim.x + threadIdx.x; i < n4;
         i += (int64_t)gridDim.x * blockDim.x) {
        float4 a = ((const float4*)x0)[i];
        float4 b = ((const float4*)x1)[i];
        ushort4 ua, ub;
        ua.x = f2bf(a.x); ua.y = f2bf(a.y); ua.z = f2bf(a.z); ua.w = f2bf(a.w);
        ub.x = f2bf(b.x); ub.y = f2bf(b.y); ub.z = f2bf(b.z); ub.w = f2bf(b.w);
        o0[i] = ua;
        o1[i] = ub;
    }
}

// ---------------- kernel 0b: convert weights f32 -> bf16 ----------------
__global__ void convert_w(const float* __restrict__ w0, const float* __restrict__ w1,
                          uint16_t* __restrict__ wbf) {
    const int64_t n4 = (int64_t)VD * HD / 4;
    ushort4* o0 = (ushort4*)wbf;
    ushort4* o1 = (ushort4*)(wbf + (int64_t)VD * HD);
    for (int64_t i = blockIdx.x * (int64_t)blockDim.x + threadIdx.x; i < n4;
         i += (int64_t)gridDim.x * blockDim.x) {
        float4 a = ((const float4*)w0)[i];
        float4 b = ((const float4*)w1)[i];
        ushort4 ua, ub;
        ua.x = f2bf(a.x); ua.y = f2bf(a.y); ua.z = f2bf(a.z); ua.w = f2bf(a.w);
        ub.x = f2bf(b.x); ub.y = f2bf(b.y); ub.z = f2bf(b.z); ub.w = f2bf(b.w);
        o0[i] = ua;
        o1[i] = ub;
    }
}

// 16 MFMA cluster (one mi-pair quadrant x K=64), ks-major: 8 independent then 8.
__device__ __forceinline__ void mfma16(
    const short8& a0k0, const short8& a0k1, const short8& a1k0, const short8& a1k1,
    const short8 (&bfr)[4][2], f32x4* acc0, f32x4* acc1)
{
    __builtin_amdgcn_s_setprio(1);
#pragma unroll
    for (int ni = 0; ni < 4; ++ni)
        acc0[ni] = __builtin_amdgcn_mfma_f32_16x16x32_bf16(a0k0, bfr[ni][0], acc0[ni], 0, 0, 0);
#pragma unroll
    for (int ni = 0; ni < 4; ++ni)
        acc1[ni] = __builtin_amdgcn_mfma_f32_16x16x32_bf16(a1k0, bfr[ni][0], acc1[ni], 0, 0, 0);
#pragma unroll
    for (int ni = 0; ni < 4; ++ni)
        acc0[ni] = __builtin_amdgcn_mfma_f32_16x16x32_bf16(a0k1, bfr[ni][1], acc0[ni], 0, 0, 0);
#pragma unroll
    for (int ni = 0; ni < 4; ++ni)
        acc1[ni] = __builtin_amdgcn_mfma_f32_16x16x32_bf16(a1k1, bfr[ni][1], acc1[ni], 0, 0, 0);
    __builtin_amdgcn_s_setprio(0);
}

// ---------------- main GEMM tile body: A via LDS dbuf, B direct-from-global ----------------
// vmcnt ledger per wave per tile: enter with B(t) 8 outstanding (issued at end of t-1).
// +4 A-gloads(t+1) -> 12. Compiler auto-waits vmcnt(4) before first B-use (retires B(t)).
// Tile end: +8 B(t+1) -> 12; manual vmcnt(8) retires the 4 A-gloads (NXT staged) -> barrier.
template<int CUR>
__device__ __forceinline__ void tile_body(
    int t,
    const uint16_t* __restrict__ agp,
    const uint16_t* (&bgn)[4],
    char* aLdst,
    const char* pA0, const char* pA1,
    short8 (&bfr)[4][2],
    f32x4 (&acc)[8][4])
{
    constexpr int CB  = CUR * 32768;
    constexpr int NXB = (CUR ^ 1) * 32768;
    const bool more = (t + 1) < KT;
    const int ko = (t + 1) * BKT;

    // ---- stage A(t+1) into NXT (oldest vmem ops of this tile) ----
    if (more) {
#pragma unroll
        for (int j = 0; j < 4; ++j)
            gload16(agp + (size_t)(j * 32) * HD + ko, aLdst + NXB + j * 4096);
    }
    SBAR;

    // ---- quadrant-pipelined compute on CUR ----
    short8 aX0 = *(const short8*)(pA0 + 0 * 2048 + CB);
    short8 aX1 = *(const short8*)(pA1 + 0 * 2048 + CB);
    short8 aX2 = *(const short8*)(pA0 + 1 * 2048 + CB);
    short8 aX3 = *(const short8*)(pA1 + 1 * 2048 + CB);
    short8 aY0 = *(const short8*)(pA0 + 2 * 2048 + CB);
    short8 aY1 = *(const short8*)(pA1 + 2 * 2048 + CB);
    short8 aY2 = *(const short8*)(pA0 + 3 * 2048 + CB);
    short8 aY3 = *(const short8*)(pA1 + 3 * 2048 + CB);
    SBAR;
    mfma16(aX0, aX1, aX2, aX3, bfr, acc[0], acc[1]);   // q0 (mi 0,1)
    SBAR;
    aX0 = *(const short8*)(pA0 + 4 * 2048 + CB);
    aX1 = *(const short8*)(pA1 + 4 * 2048 + CB);
    aX2 = *(const short8*)(pA0 + 5 * 2048 + CB);
    aX3 = *(const short8*)(pA1 + 5 * 2048 + CB);
    SBAR;
    mfma16(aY0, aY1, aY2, aY3, bfr, acc[2], acc[3]);   // q1 (mi 2,3)
    SBAR;
    aY0 = *(const short8*)(pA0 + 6 * 2048 + CB);
    aY1 = *(const short8*)(pA1 + 6 * 2048 + CB);
    aY2 = *(const short8*)(pA0 + 7 * 2048 + CB);
    aY3 = *(const short8*)(pA1 + 7 * 2048 + CB);
    SBAR;
    mfma16(aX0, aX1, aX2, aX3, bfr, acc[4], acc[5]);   // q2 (mi 4,5)
    SBAR;
    mfma16(aY0, aY1, aY2, aY3, bfr, acc[6], acc[7]);   // q3 (mi 6,7)
    SBAR;

    // ---- issue B(t+1) fragment loads (pure global reads; cross the barrier) ----
    if (more) {
#pragma unroll
        for (int ni = 0; ni < 4; ++ni) {
            bgn[ni] += BKT;
            bfr[ni][0] = *(const short8*)(bgn[ni]);
            bfr[ni][1] = *(const short8*)(bgn[ni] + 32);
        }
    }
    SBAR;
    asm volatile("s_waitcnt vmcnt(8)" ::: "memory");   // retire my 4 A-gloads; B(t+1) in flight
    SBAR;
    __builtin_amdgcn_s_barrier();
    SBAR;
}

// ---------------- kernel 1 (main): 256x256 GEMM + LSE partials ----------------
__global__ __launch_bounds__(512, 2) void gemm_lse_bf(
    const uint16_t* __restrict__ xbf, const uint16_t* __restrict__ wbf,
    const float* __restrict__ b0, const float* __restrict__ b1,
    const int* __restrict__ target,
    float* __restrict__ partials, float* __restrict__ tgtlog)
{
    __shared__ uint16_t As[2 * BM * BKT];  // 64 KB (2 buffers) — A only; B is direct

    const int orig = blockIdx.x;
    const int wgid = (orig & 7) * (NWG2 / 8) + (orig >> 3);
    const int mb    = wgid & 7;
    const int rest  = wgid >> 3;
    const int nb    = rest % NB;
    const int model = rest / NB;

    const uint16_t* xb = xbf + (size_t)model * BT * HD;
    const uint16_t* wb = wbf + (size_t)model * VD * HD;
    const float* bias  = model ? b1 : b0;

    const int row0 = mb * BM;
    const int c0   = nb * BN;

    const int tid    = threadIdx.x;
    const int lane   = tid & 63;
    const int wid    = tid >> 6;       // 0..7
    const int wr     = wid >> 2;       // 0..1  (M half)
    const int wc     = wid & 3;        // 0..3  (N quarter)

    const int lane15 = lane & 15;
    const int kg     = lane >> 4;
    const int swz    = (lane & 7) << 4;

    // A staging (verified): wave stages its A-half quadrant; LDS dest linear 1KB
    // chunks, global source slot pre-swizzled by (row&7).
    const int srow8 = lane >> 3;               // 0..7
    const int slot  = (lane & 7) ^ srow8;      // pre-swizzled source slot
    const uint16_t* agp = xb + (size_t)(row0 + wr * 128 + wc * 8 + srow8) * HD + slot * 8;
    char* aLdst = (char*)As + wr * 16384 + wc * 1024;          // + j*4096 + buf*32768

    // A fragment read base pointers (proven 0-conflict 16x16 pattern)
    const int arow_b = wr * 128 + lane15;
    const char* pA0 = (const char*)As + ((arow_b * 128 + 0  + kg * 16) ^ swz);
    const char* pA1 = (const char*)As + ((arow_b * 128 + 64 + kg * 16) ^ swz);

    // B direct-fragment base pointers (per ni): row = c0 + wc*64 + ni*16 + lane15,
    // k-base = kg*8; per-tile advance += BKT; ks offset = +32 elements.
    const uint16_t* bgn[4];
#pragma unroll
    for (int ni = 0; ni < 4; ++ni)
        bgn[ni] = wb + (size_t)(c0 + wc * 64 + ni * 16 + lane15) * HD + kg * 8;

    f32x4 acc[8][4];
#pragma unroll
    for (int i = 0; i < 8; ++i)
#pragma unroll
        for (int j = 0; j < 4; ++j) acc[i][j] = (f32x4){0.f, 0.f, 0.f, 0.f};

    short8 bfr[4][2];

    // prologue: stage A(0) into buf 0; issue B(0); retire A-gloads; barrier
#pragma unroll
    for (int j = 0; j < 4; ++j)
        gload16(agp + (size_t)(j * 32) * HD, aLdst + j * 4096);
#pragma unroll
    for (int ni = 0; ni < 4; ++ni) {
        bfr[ni][0] = *(const short8*)(bgn[ni]);
        bfr[ni][1] = *(const short8*)(bgn[ni] + 32);
    }
    SBAR; asm volatile("s_waitcnt vmcnt(8)" ::: "memory"); SBAR;
    __builtin_amdgcn_s_barrier();
    SBAR;

    for (int t2 = 0; t2 < KT; t2 += 2) {
        tile_body<0>(t2,     agp, bgn, aLdst, pA0, pA1, bfr, acc);
        tile_body<1>(t2 + 1, agp, bgn, aLdst, pA0, pA1, bfr, acc);
    }

    // ---- epilogue: bias, per-row max/sumexp over this wave's 64 cols ----
    float bv4[4];
#pragma unroll
    for (int ni = 0; ni < 4; ++ni) bv4[ni] = bias[c0 + wc * 64 + ni * 16 + lane15];

#pragma unroll
    for (int mi = 0; mi < 8; ++mi) {
        const int grow_base = row0 + wr * 128 + mi * 16 + kg * 4;
#pragma unroll
        for (int j = 0; j < 4; ++j) {
            const int grow = grow_base + j;
            float v[4];
#pragma unroll
            for (int ni = 0; ni < 4; ++ni) v[ni] = acc[mi][ni][j] + bv4[ni];
            float m = fmaxf(fmaxf(v[0], v[1]), fmaxf(v[2], v[3]));
#pragma unroll
            for (int msk = 1; msk < 16; msk <<= 1)
                m = fmaxf(m, __shfl_xor(m, msk));
            float s = __expf(v[0] - m) + __expf(v[1] - m) +
                      __expf(v[2] - m) + __expf(v[3] - m);
#pragma unroll
            for (int msk = 1; msk < 16; msk <<= 1)
                s += __shfl_xor(s, msk);
            const int tg = target[grow];
#pragma unroll
            for (int ni = 0; ni < 4; ++ni) {
                const int gcol = c0 + wc * 64 + ni * 16 + lane15;
                if (tg == gcol) tgtlog[model * BT + grow] = v[ni];
            }
            if (lane15 == 0) {
                const size_t po = ((size_t)(model * BT + grow) * NCHUNK + nb * 4 + wc) * 2;
                partials[po]     = m;
                partials[po + 1] = s;
            }
        }
    }
}

// ---------------- kernel 1 (fallback, f32 weights): R1 structure ----------------
__global__ __launch_bounds__(256) void gemm_lse_f32(
    const uint16_t* __restrict__ xbf,
    const float* __restrict__ w0, const float* __restrict__ b0,
    const float* __restrict__ w1, const float* __restrict__ b1,
    const int* __restrict__ target,
    float* __restrict__ partials, float* __restrict__ tgtlog)
{
    const int orig = blockIdx.x;               // grid 8000
    const int wgid = (orig & 7) * 1000 + (orig >> 3);
    const int mb    = wgid & 7;
    const int rest  = wgid >> 3;
    const int chunk = rest % 500;
    const int model = rest / 500;

    const float* w    = model ? w1 : w0;
    const float* bias = model ? b1 : b0;
    const uint16_t* xb = xbf + (size_t)model * BT * HD;

    const int row0 = mb * 256;
    const int c0   = chunk * 64;

    const int tid  = threadIdx.x;
    const int lane = tid & 63;
    const int wid  = tid >> 6;

    __shared__ uint16_t As_[256 * 64];
    __shared__ uint16_t Bs_[64 * 64];

    f32x4 acc[4][4];
#pragma unroll
    for (int i = 0; i < 4; ++i)
#pragma unroll
        for (int j = 0; j < 4; ++j) acc[i][j] = (f32x4){0.f, 0.f, 0.f, 0.f};

    const int srow8 = lane >> 3;
    const int slot  = (lane & 7) ^ srow8;
    const uint16_t* agsrc = xb + (size_t)(row0 + wid * 64 + srow8) * HD + slot * 8;
    char* aldst = (char*)As_ + wid * 8192;

    const int ss   = tid & 7;
    const int srow = tid >> 3;
    const int swz_w = (srow & 7) << 4;
    const float* bptr = w + (size_t)(c0 + srow) * HD + ss * 8;

    const int lane15 = lane & 15;
    const int kg     = lane >> 4;
    const int swz_r  = (lane & 7) << 4;

    for (int kt = 0; kt < 64; ++kt) {
        const int kofs = kt * 64;
#pragma unroll
        for (int c = 0; c < 8; ++c)
            gload16(agsrc + (size_t)c * 8 * HD + kofs, aldst + c * 1024);
        {
            float4 bv[2][2];
#pragma unroll
            for (int r = 0; r < 2; ++r) {
                const float* p = bptr + (size_t)r * 32 * HD + kofs;
                bv[r][0] = *(const float4*)(p);
                bv[r][1] = *(const float4*)(p + 4);
            }
#pragma unroll
            for (int r = 0; r < 2; ++r) {
                const int row_l = srow + r * 32;
                float fv[8] = {bv[r][0].x, bv[r][0].y, bv[r][0].z, bv[r][0].w,
                               bv[r][1].x, bv[r][1].y, bv[r][1].z, bv[r][1].w};
                uint32_t pk[4];
#pragma unroll
                for (int e = 0; e < 4; ++e)
                    pk[e] = (uint32_t)f2bf(fv[2 * e]) | ((uint32_t)f2bf(fv[2 * e + 1]) << 16);
                const int off = (row_l * 128 + ss * 16) ^ swz_w;
                *(uint4*)((char*)Bs_ + off) = *(uint4*)pk;
            }
        }
        __syncthreads();
#pragma unroll
        for (int ks = 0; ks < 2; ++ks) {
            short8 af[4], bf[4];
#pragma unroll
            for (int mi = 0; mi < 4; ++mi) {
                const int arow = wid * 64 + mi * 16 + lane15;
                const int off = (arow * 128 + ks * 64 + kg * 16) ^ swz_r;
                af[mi] = *(const short8*)((const char*)As_ + off);
            }
#pragma unroll
            for (int ni = 0; ni < 4; ++ni) {
                const int brow = ni * 16 + lane15;
                const int off = (brow * 128 + ks * 64 + kg * 16) ^ swz_r;
                bf[ni] = *(const short8*)((const char*)Bs_ + off);
            }
#pragma unroll
            for (int mi = 0; mi < 4; ++mi)
#pragma unroll
                for (int ni = 0; ni < 4; ++ni)
                    acc[mi][ni] = __builtin_amdgcn_mfma_f32_16x16x32_bf16(
                        af[mi], bf[ni], acc[mi][ni], 0, 0, 0);
        }
        __syncthreads();
    }

    float bv4[4];
#pragma unroll
    for (int ni = 0; ni < 4; ++ni) bv4[ni] = bias[c0 + ni * 16 + lane15];

#pragma unroll
    for (int mi = 0; mi < 4; ++mi) {
        const int grow_base = row0 + wid * 64 + mi * 16 + kg * 4;
#pragma unroll
        for (int j = 0; j < 4; ++j) {
            const int grow = grow_base + j;
            float v[4];
#pragma unroll
            for (int ni = 0; ni < 4; ++ni) v[ni] = acc[mi][ni][j] + bv4[ni];
            float m = fmaxf(fmaxf(v[0], v[1]), fmaxf(v[2], v[3]));
#pragma unroll
            for (int msk = 1; msk < 16; msk <<= 1)
                m = fmaxf(m, __shfl_xor(m, msk));
            float s = __expf(v[0] - m) + __expf(v[1] - m) +
                      __expf(v[2] - m) + __expf(v[3] - m);
#pragma unroll
            for (int msk = 1; msk < 16; msk <<= 1)
                s += __shfl_xor(s, msk);
            const int tg = target[grow];
#pragma unroll
            for (int ni = 0; ni < 4; ++ni) {
                const int gcol = c0 + ni * 16 + lane15;
                if (tg == gcol) tgtlog[model * BT + grow] = v[ni];
            }
            if (lane15 == 0) {
                const size_t po = ((size_t)(model * BT + grow) * NCHUNK + chunk) * 2;
                partials[po]     = m;
                partials[po + 1] = s;
            }
        }
    }
}

// ---------------- kernel 2: combine chunk partials -> lse -> per-token logp ----------------
__global__ void lse_reduce(const float* __restrict__ partials,
                           const float* __restrict__ tgtlog,
                           float* __restrict__ logp) {
    const int gw = blockIdx.x * (blockDim.x >> 6) + (threadIdx.x >> 6);
    if (gw >= 2 * BT) return;
    const int lane = threadIdx.x & 63;
    const float* p = partials + (size_t)gw * NCHUNK * 2;

    float m = -1e30f;
#pragma unroll
    for (int i = 0; i < 8; ++i) {
        const int c = lane + i * 64;
        if (c < NCHUNK) m = fmaxf(m, p[c * 2]);
    }
#pragma unroll
    for (int msk = 1; msk < 64; msk <<= 1) m = fmaxf(m, __shfl_xor(m, msk));
    float s = 0.f;
#pragma unroll
    for (int i = 0; i < 8; ++i) {
        const int c = lane + i * 64;
        if (c < NCHUNK) s += p[c * 2 + 1] * __expf(p[c * 2] - m);
    }
#pragma unroll
    for (int msk = 1; msk < 64; msk <<= 1) s += __shfl_xor(s, msk);
    if (lane == 0) {
        const float lse = m + __logf(s);
        logp[gw] = tgtlog[gw] - lse;
    }
}

// ---------------- kernel 3: KTO loss ----------------
__global__ void final_loss(const float* __restrict__ logp, const int* __restrict__ target,
                           const int* __restrict__ pref, const float* __restrict__ kl,
                           float* __restrict__ out) {
    const int t = threadIdx.x;          // 512 threads
    const int lane = t & 63, wv = t >> 6;
    __shared__ float rp[4][8], rr[4][8], rm[4][8];
#pragma unroll
    for (int b = 0; b < 4; ++b) {
        const int idx = b * TT + t;
        const int tg = target[idx];
        const bool mk = (tg != IGNORE_IDX);
        float lp = mk ? logp[idx] : 0.f;
        float lr = mk ? logp[BT + idx] : 0.f;
        float mc = mk ? 1.f : 0.f;
        for (int off = 32; off; off >>= 1) {
            lp += __shfl_down(lp, off);
            lr += __shfl_down(lr, off);
            mc += __shfl_down(mc, off);
        }
        if (lane == 0) { rp[b][wv] = lp; rr[b][wv] = lr; rm[b][wv] = mc; }
    }
    __syncthreads();
    if (t == 0) {
        float loss = 0.f;
        for (int b = 0; b < 4; ++b) {
            float sp = 0.f, sr = 0.f, sm = 0.f;
            for (int i = 0; i < 8; ++i) { sp += rp[b][i]; sr += rr[b][i]; sm += rm[b][i]; }
            const float denom = fmaxf(sm, 1.f);
            const float lrb = (sp - sr) / denom;
            const float mult = pref[b] ? 1.f : -1.f;
            const float z = 0.1f * (lrb - kl[0]) * mult;
            loss += 1.f / (1.f + __expf(z));   // 1 - sigmoid(z)
        }
        out[0] = loss * 0.25f;
    }
}

extern "C" void kernel_launch(void* const* d_in, const int* in_sizes, int n_in,
                              void* d_out, int out_size, void* d_ws, size_t ws_size,
                              hipStream_t stream) {
    const float* x    = (const float*)d_in[0];
    const float* w0   = (const float*)d_in[1];
    const float* b0   = (const float*)d_in[2];
    const int*   tgt  = (const int*)d_in[3];
    const int*   pref = (const int*)d_in[4];
    const float* xr   = (const float*)d_in[5];
    const float* w1   = (const float*)d_in[6];
    const float* b1   = (const float*)d_in[7];
    const float* kl   = (const float*)d_in[8];
    float* out = (float*)d_out;

    // ws layout: xbf | partials | tgtlog | logp | [wbf if it fits]
    const size_t xbf_b  = (size_t)2 * BT * HD * 2;          // 33.55 MB
    const size_t part_b = (size_t)2 * BT * NCHUNK * 2 * 4;  // 16.38 MB
    const size_t tl_b   = (size_t)2 * BT * 4;
    const size_t wbf_b  = (size_t)2 * VD * HD * 2;          // 524.3 MB

    char* wp = (char*)d_ws;
    uint16_t* xbf     = (uint16_t*)wp;                 wp += xbf_b;
    float*    partials = (float*)wp;                   wp += part_b;
    float*    tgtlog   = (float*)wp;                   wp += tl_b;
    float*    logp     = (float*)wp;                   wp += tl_b;
    uint16_t* wbf      = (uint16_t*)wp;
    const bool use_wbf = ws_size >= (xbf_b + part_b + 2 * tl_b + wbf_b);

    hipLaunchKernelGGL(convert_x, dim3(1024), dim3(256), 0, stream, x, xr, xbf);
    if (use_wbf) {
        hipLaunchKernelGGL(convert_w, dim3(4096), dim3(256), 0, stream, w0, w1, wbf);
        hipLaunchKernelGGL(gemm_lse_bf, dim3(NWG2), dim3(512), 0, stream,
                           xbf, wbf, b0, b1, tgt, partials, tgtlog);
    } else {
        hipLaunchKernelGGL(gemm_lse_f32, dim3(8000), dim3(256), 0, stream,
                           xbf, w0, b0, w1, b1, tgt, partials, tgtlog);
    }
    hipLaunchKernelGGL(lse_reduce, dim3(2 * BT / 4), dim3(256), 0, stream,
                       partials, tgtlog, logp);
    hipLaunchKernelGGL(final_loss, dim3(1), dim3(512), 0, stream, logp, tgt, pref, kl, out);
}

// Round 10
// 1482.763 us; speedup vs baseline: 1.2680x; 1.2680x over previous
//
#include <hip/hip_runtime.h>
#include <hip/hip_bf16.h>
#include <stdint.h>

#define HD 4096
#define VD 32000
#define BT 2048        // B*T rows
#define TT 512
#define IGNORE_IDX (-100)

// bf16 8-wave main GEMM geometry
#define BM 256
#define BN 256
#define BKT 64
#define KT (HD / BKT)          // 64 K-tiles
#define NB (VD / BN)           // 125
#define MB (BT / BM)           // 8
#define NWG2 (MB * NB * 2)     // 2000

// partials granularity (64 columns per chunk) — shared with f32 fallback
#define NCHUNK (VD / 64)       // 500

typedef __attribute__((ext_vector_type(8))) short short8;
typedef __attribute__((ext_vector_type(4))) float f32x4;

__device__ __forceinline__ uint16_t f2bf(float f) {
    uint32_t u = __float_as_uint(f);
    u += 0x7FFFu + ((u >> 16) & 1u);   // round-to-nearest-even
    return (uint16_t)(u >> 16);
}

__device__ __forceinline__ void gload16(const void* g, void* l) {
    __builtin_amdgcn_global_load_lds(
        (const __attribute__((address_space(1))) void*)g,
        (__attribute__((address_space(3))) void*)l, 16, 0, 0);
}

// ---------------- kernel 0a: convert x inputs f32 -> bf16 ----------------
__global__ void convert_x(const float* __restrict__ x0, const float* __restrict__ x1,
                          uint16_t* __restrict__ xbf) {
    const int64_t n4 = (int64_t)BT * HD / 4;
    ushort4* o0 = (ushort4*)xbf;
    ushort4* o1 = (ushort4*)(xbf + (int64_t)BT * HD);
    for (int64_t i = blockIdx.x * (int64_t)blockDim.x + threadIdx.x; i < n4;
         i += (int64_t)gridDim.x * blockDim.x) {
        float4 a = ((const float4*)x0)[i];
        float4 b = ((const float4*)x1)[i];
        ushort4 ua, ub;
        ua.x = f2bf(a.x); ua.y = f2bf(a.y); ua.z = f2bf(a.z); ua.w = f2bf(a.w);
        ub.x = f2bf(b.x); ub.y = f2bf(b.y); ub.z = f2bf(b.z); ub.w = f2bf(b.w);
        o0[i] = ua;
        o1[i] = ub;
    }
}

// ---------------- kernel 0b: convert weights f32 -> bf16 ----------------
__global__ void convert_w(const float* __restrict__ w0, const float* __restrict__ w1,
                          uint16_t* __restrict__ wbf) {
    const int64_t n4 = (int64_t)VD * HD / 4;
    ushort4* o0 = (ushort4*)wbf;
    ushort4* o1 = (ushort4*)(wbf + (int64_t)VD * HD);
    for (int64_t i = blockIdx.x * (int64_t)blockDim.x + threadIdx.x; i < n4;
         i += (int64_t)gridDim.x * blockDim.x) {
        float4 a = ((const float4*)w0)[i];
        float4 b = ((const float4*)w1)[i];
        ushort4 ua, ub;
        ua.x = f2bf(a.x); ua.y = f2bf(a.y); ua.z = f2bf(a.z); ua.w = f2bf(a.w);
        ub.x = f2bf(b.x); ub.y = f2bf(b.y); ub.z = f2bf(b.z); ub.w = f2bf(b.w);
        o0[i] = ua;
        o1[i] = ub;
    }
}

// 16 MFMA cluster (one mi-pair quadrant x K=64), ks-major, NO setprio/fences:
// the compiler is free to interleave these with the ds_reads of later quadrants.
__device__ __forceinline__ void mfma16(
    const short8& a0k0, const short8& a0k1, const short8& a1k0, const short8& a1k1,
    const short8 (&bfr)[4][2], f32x4* acc0, f32x4* acc1)
{
#pragma unroll
    for (int ni = 0; ni < 4; ++ni)
        acc0[ni] = __builtin_amdgcn_mfma_f32_16x16x32_bf16(a0k0, bfr[ni][0], acc0[ni], 0, 0, 0);
#pragma unroll
    for (int ni = 0; ni < 4; ++ni)
        acc1[ni] = __builtin_amdgcn_mfma_f32_16x16x32_bf16(a1k0, bfr[ni][0], acc1[ni], 0, 0, 0);
#pragma unroll
    for (int ni = 0; ni < 4; ++ni)
        acc0[ni] = __builtin_amdgcn_mfma_f32_16x16x32_bf16(a0k1, bfr[ni][1], acc0[ni], 0, 0, 0);
#pragma unroll
    for (int ni = 0; ni < 4; ++ni)
        acc1[ni] = __builtin_amdgcn_mfma_f32_16x16x32_bf16(a1k1, bfr[ni][1], acc1[ni], 0, 0, 0);
}

// ---------------- main GEMM tile body: 1 barrier/tile, compiler-scheduled ----------------
// {stage 8 gloads -> NXT | compute CUR fully compiler-scheduled (ds_reads pipelined
// under MFMAs with counted lgkmcnt) | vmcnt(0) (loads issued a tile earlier) | s_barrier}.
// NO sched_barrier anywhere (m141 lesson: SBAR walls serialize read->MFMA per wave).
template<int CUR>
__device__ __forceinline__ void tile_body(
    int t,
    const uint16_t* __restrict__ agp, const uint16_t* __restrict__ bgp,
    char* aLdst, char* bLdst,
    const char* pA0, const char* pA1, const char* pB0, const char* pB1,
    f32x4 (&acc)[8][4])
{
    constexpr int CB  = CUR * 32768;
    constexpr int NXB = (CUR ^ 1) * 32768;
    const bool more = (t + 1) < KT;
    const int ko = (t + 1) * BKT;

    if (more) {
#pragma unroll
        for (int j = 0; j < 4; ++j)
            gload16(bgp + (size_t)(j * 32) * HD + ko, bLdst + NXB + j * 4096);
#pragma unroll
        for (int j = 0; j < 4; ++j)
            gload16(agp + (size_t)(j * 32) * HD + ko, aLdst + NXB + j * 4096);
    }

    short8 bfr[4][2];
#pragma unroll
    for (int ni = 0; ni < 4; ++ni) {
        bfr[ni][0] = *(const short8*)(pB0 + ni * 2048 + CB);
        bfr[ni][1] = *(const short8*)(pB1 + ni * 2048 + CB);
    }
#pragma unroll
    for (int p = 0; p < 4; ++p) {
        const short8 a0 = *(const short8*)(pA0 + (2 * p) * 2048 + CB);
        const short8 a1 = *(const short8*)(pA1 + (2 * p) * 2048 + CB);
        const short8 a2 = *(const short8*)(pA0 + (2 * p + 1) * 2048 + CB);
        const short8 a3 = *(const short8*)(pA1 + (2 * p + 1) * 2048 + CB);
        mfma16(a0, a1, a2, a3, bfr, acc[2 * p], acc[2 * p + 1]);
    }

    asm volatile("s_waitcnt vmcnt(0)" ::: "memory");
    __builtin_amdgcn_s_barrier();
}

// ---------------- kernel 1 (main): 256x256 GEMM + LSE partials ----------------
__global__ __launch_bounds__(512, 2) void gemm_lse_bf(
    const uint16_t* __restrict__ xbf, const uint16_t* __restrict__ wbf,
    const float* __restrict__ b0, const float* __restrict__ b1,
    const int* __restrict__ target,
    float* __restrict__ partials, float* __restrict__ tgtlog)
{
    __shared__ uint16_t As[2 * BM * BKT];  // 64 KB (2 buffers)
    __shared__ uint16_t Bs[2 * BN * BKT];  // 64 KB

    const int orig = blockIdx.x;
    const int wgid = (orig & 7) * (NWG2 / 8) + (orig >> 3);
    const int mb    = wgid & 7;
    const int rest  = wgid >> 3;
    const int nb    = rest % NB;
    const int model = rest / NB;

    const uint16_t* xb = xbf + (size_t)model * BT * HD;
    const uint16_t* wb = wbf + (size_t)model * VD * HD;
    const float* bias  = model ? b1 : b0;

    const int row0 = mb * BM;
    const int c0   = nb * BN;

    const int tid    = threadIdx.x;
    const int lane   = tid & 63;
    const int wid    = tid >> 6;       // 0..7
    const int wr     = wid >> 2;       // 0..1  (M half)
    const int wc     = wid & 3;        // 0..3  (N quarter)

    const int lane15 = lane & 15;
    const int kg     = lane >> 4;
    const int swz    = (lane & 7) << 4;

    // wave-local staging (verified R4/R5): wave stages its A-half and B-half
    // quadrants; LDS dest linear 1KB chunks, global source slot pre-swizzled.
    const int srow8 = lane >> 3;               // 0..7
    const int slot  = (lane & 7) ^ srow8;      // pre-swizzled source slot
    const uint16_t* agp = xb + (size_t)(row0 + wr * 128 + wc * 8 + srow8) * HD + slot * 8;
    const int bq = wr * 2 + (wc & 1);          // 0..3: stager index within B-half
    const uint16_t* bgp = wb + (size_t)(c0 + (wc >> 1) * 128 + bq * 8 + srow8) * HD + slot * 8;
    char* aLdst = (char*)As + wr * 16384 + wc * 1024;          // + j*4096 + buf*32768
    char* bLdst = (char*)Bs + (wc >> 1) * 16384 + bq * 1024;   // + j*4096 + buf*32768

    // fragment read base pointers (proven 0-conflict 16x16 pattern)
    const int arow_b = wr * 128 + lane15;
    const int brow_b = wc * 64 + lane15;
    const char* pA0 = (const char*)As + ((arow_b * 128 + 0  + kg * 16) ^ swz);
    const char* pA1 = (const char*)As + ((arow_b * 128 + 64 + kg * 16) ^ swz);
    const char* pB0 = (const char*)Bs + ((brow_b * 128 + 0  + kg * 16) ^ swz);
    const char* pB1 = (const char*)Bs + ((brow_b * 128 + 64 + kg * 16) ^ swz);

    f32x4 acc[8][4];
#pragma unroll
    for (int i = 0; i < 8; ++i)
#pragma unroll
        for (int j = 0; j < 4; ++j) acc[i][j] = (f32x4){0.f, 0.f, 0.f, 0.f};

    // prologue: stage tile 0 into buf 0, drain, barrier
#pragma unroll
    for (int j = 0; j < 4; ++j)
        gload16(bgp + (size_t)(j * 32) * HD, bLdst + j * 4096);
#pragma unroll
    for (int j = 0; j < 4; ++j)
        gload16(agp + (size_t)(j * 32) * HD, aLdst + j * 4096);
    asm volatile("s_waitcnt vmcnt(0)" ::: "memory");
    __builtin_amdgcn_s_barrier();

    for (int t2 = 0; t2 < KT; t2 += 2) {
        tile_body<0>(t2,     agp, bgp, aLdst, bLdst, pA0, pA1, pB0, pB1, acc);
        tile_body<1>(t2 + 1, agp, bgp, aLdst, bLdst, pA0, pA1, pB0, pB1, acc);
    }

    // ---- epilogue: bias, per-row max/sumexp over this wave's 64 cols ----
    float bv4[4];
#pragma unroll
    for (int ni = 0; ni < 4; ++ni) bv4[ni] = bias[c0 + wc * 64 + ni * 16 + lane15];

#pragma unroll
    for (int mi = 0; mi < 8; ++mi) {
        const int grow_base = row0 + wr * 128 + mi * 16 + kg * 4;
#pragma unroll
        for (int j = 0; j < 4; ++j) {
            const int grow = grow_base + j;
            float v[4];
#pragma unroll
            for (int ni = 0; ni < 4; ++ni) v[ni] = acc[mi][ni][j] + bv4[ni];
            float m = fmaxf(fmaxf(v[0], v[1]), fmaxf(v[2], v[3]));
#pragma unroll
            for (int msk = 1; msk < 16; msk <<= 1)
                m = fmaxf(m, __shfl_xor(m, msk));
            float s = __expf(v[0] - m) + __expf(v[1] - m) +
                      __expf(v[2] - m) + __expf(v[3] - m);
#pragma unroll
            for (int msk = 1; msk < 16; msk <<= 1)
                s += __shfl_xor(s, msk);
            const int tg = target[grow];
#pragma unroll
            for (int ni = 0; ni < 4; ++ni) {
                const int gcol = c0 + wc * 64 + ni * 16 + lane15;
                if (tg == gcol) tgtlog[model * BT + grow] = v[ni];
            }
            if (lane15 == 0) {
                const size_t po = ((size_t)(model * BT + grow) * NCHUNK + nb * 4 + wc) * 2;
                partials[po]     = m;
                partials[po + 1] = s;
            }
        }
    }
}

// ---------------- kernel 1 (fallback, f32 weights): R1 structure ----------------
__global__ __launch_bounds__(256) void gemm_lse_f32(
    const uint16_t* __restrict__ xbf,
    const float* __restrict__ w0, const float* __restrict__ b0,
    const float* __restrict__ w1, const float* __restrict__ b1,
    const int* __restrict__ target,
    float* __restrict__ partials, float* __restrict__ tgtlog)
{
    const int orig = blockIdx.x;               // grid 8000
    const int wgid = (orig & 7) * 1000 + (orig >> 3);
    const int mb    = wgid & 7;
    const int rest  = wgid >> 3;
    const int chunk = rest % 500;
    const int model = rest / 500;

    const float* w    = model ? w1 : w0;
    const float* bias = model ? b1 : b0;
    const uint16_t* xb = xbf + (size_t)model * BT * HD;

    const int row0 = mb * 256;
    const int c0   = chunk * 64;

    const int tid  = threadIdx.x;
    const int lane = tid & 63;
    const int wid  = tid >> 6;

    __shared__ uint16_t As_[256 * 64];
    __shared__ uint16_t Bs_[64 * 64];

    f32x4 acc[4][4];
#pragma unroll
    for (int i = 0; i < 4; ++i)
#pragma unroll
        for (int j = 0; j < 4; ++j) acc[i][j] = (f32x4){0.f, 0.f, 0.f, 0.f};

    const int srow8 = lane >> 3;
    const int slot  = (lane & 7) ^ srow8;
    const uint16_t* agsrc = xb + (size_t)(row0 + wid * 64 + srow8) * HD + slot * 8;
    char* aldst = (char*)As_ + wid * 8192;

    const int ss   = tid & 7;
    const int srow = tid >> 3;
    const int swz_w = (srow & 7) << 4;
    const float* bptr = w + (size_t)(c0 + srow) * HD + ss * 8;

    const int lane15 = lane & 15;
    const int kg     = lane >> 4;
    const int swz_r  = (lane & 7) << 4;

    for (int kt = 0; kt < 64; ++kt) {
        const int kofs = kt * 64;
#pragma unroll
        for (int c = 0; c < 8; ++c)
            gload16(agsrc + (size_t)c * 8 * HD + kofs, aldst + c * 1024);
        {
            float4 bv[2][2];
#pragma unroll
            for (int r = 0; r < 2; ++r) {
                const float* p = bptr + (size_t)r * 32 * HD + kofs;
                bv[r][0] = *(const float4*)(p);
                bv[r][1] = *(const float4*)(p + 4);
            }
#pragma unroll
            for (int r = 0; r < 2; ++r) {
                const int row_l = srow + r * 32;
                float fv[8] = {bv[r][0].x, bv[r][0].y, bv[r][0].z, bv[r][0].w,
                               bv[r][1].x, bv[r][1].y, bv[r][1].z, bv[r][1].w};
                uint32_t pk[4];
#pragma unroll
                for (int e = 0; e < 4; ++e)
                    pk[e] = (uint32_t)f2bf(fv[2 * e]) | ((uint32_t)f2bf(fv[2 * e + 1]) << 16);
                const int off = (row_l * 128 + ss * 16) ^ swz_w;
                *(uint4*)((char*)Bs_ + off) = *(uint4*)pk;
            }
        }
        __syncthreads();
#pragma unroll
        for (int ks = 0; ks < 2; ++ks) {
            short8 af[4], bf[4];
#pragma unroll
            for (int mi = 0; mi < 4; ++mi) {
                const int arow = wid * 64 + mi * 16 + lane15;
                const int off = (arow * 128 + ks * 64 + kg * 16) ^ swz_r;
                af[mi] = *(const short8*)((const char*)As_ + off);
            }
#pragma unroll
            for (int ni = 0; ni < 4; ++ni) {
                const int brow = ni * 16 + lane15;
                const int off = (brow * 128 + ks * 64 + kg * 16) ^ swz_r;
                bf[ni] = *(const short8*)((const char*)Bs_ + off);
            }
#pragma unroll
            for (int mi = 0; mi < 4; ++mi)
#pragma unroll
                for (int ni = 0; ni < 4; ++ni)
                    acc[mi][ni] = __builtin_amdgcn_mfma_f32_16x16x32_bf16(
                        af[mi], bf[ni], acc[mi][ni], 0, 0, 0);
        }
        __syncthreads();
    }

    float bv4[4];
#pragma unroll
    for (int ni = 0; ni < 4; ++ni) bv4[ni] = bias[c0 + ni * 16 + lane15];

#pragma unroll
    for (int mi = 0; mi < 4; ++mi) {
        const int grow_base = row0 + wid * 64 + mi * 16 + kg * 4;
#pragma unroll
        for (int j = 0; j < 4; ++j) {
            const int grow = grow_base + j;
            float v[4];
#pragma unroll
            for (int ni = 0; ni < 4; ++ni) v[ni] = acc[mi][ni][j] + bv4[ni];
            float m = fmaxf(fmaxf(v[0], v[1]), fmaxf(v[2], v[3]));
#pragma unroll
            for (int msk = 1; msk < 16; msk <<= 1)
                m = fmaxf(m, __shfl_xor(m, msk));
            float s = __expf(v[0] - m) + __expf(v[1] - m) +
                      __expf(v[2] - m) + __expf(v[3] - m);
#pragma unroll
            for (int msk = 1; msk < 16; msk <<= 1)
                s += __shfl_xor(s, msk);
            const int tg = target[grow];
#pragma unroll
            for (int ni = 0; ni < 4; ++ni) {
                const int gcol = c0 + ni * 16 + lane15;
                if (tg == gcol) tgtlog[model * BT + grow] = v[ni];
            }
            if (lane15 == 0) {
                const size_t po = ((size_t)(model * BT + grow) * NCHUNK + chunk) * 2;
                partials[po]     = m;
                partials[po + 1] = s;
            }
        }
    }
}

// ---------------- kernel 2: combine chunk partials -> lse -> per-token logp ----------------
__global__ void lse_reduce(const float* __restrict__ partials,
                           const float* __restrict__ tgtlog,
                           float* __restrict__ logp) {
    const int gw = blockIdx.x * (blockDim.x >> 6) + (threadIdx.x >> 6);
    if (gw >= 2 * BT) return;
    const int lane = threadIdx.x & 63;
    const float* p = partials + (size_t)gw * NCHUNK * 2;

    float m = -1e30f;
#pragma unroll
    for (int i = 0; i < 8; ++i) {
        const int c = lane + i * 64;
        if (c < NCHUNK) m = fmaxf(m, p[c * 2]);
    }
#pragma unroll
    for (int msk = 1; msk < 64; msk <<= 1) m = fmaxf(m, __shfl_xor(m, msk));
    float s = 0.f;
#pragma unroll
    for (int i = 0; i < 8; ++i) {
        const int c = lane + i * 64;
        if (c < NCHUNK) s += p[c * 2 + 1] * __expf(p[c * 2] - m);
    }
#pragma unroll
    for (int msk = 1; msk < 64; msk <<= 1) s += __shfl_xor(s, msk);
    if (lane == 0) {
        const float lse = m + __logf(s);
        logp[gw] = tgtlog[gw] - lse;
    }
}

// ---------------- kernel 3: KTO loss ----------------
__global__ void final_loss(const float* __restrict__ logp, const int* __restrict__ target,
                           const int* __restrict__ pref, const float* __restrict__ kl,
                           float* __restrict__ out) {
    const int t = threadIdx.x;          // 512 threads
    const int lane = t & 63, wv = t >> 6;
    __shared__ float rp[4][8], rr[4][8], rm[4][8];
#pragma unroll
    for (int b = 0; b < 4; ++b) {
        const int idx = b * TT + t;
        const int tg = target[idx];
        const bool mk = (tg != IGNORE_IDX);
        float lp = mk ? logp[idx] : 0.f;
        float lr = mk ? logp[BT + idx] : 0.f;
        float mc = mk ? 1.f : 0.f;
        for (int off = 32; off; off >>= 1) {
            lp += __shfl_down(lp, off);
            lr += __shfl_down(lr, off);
            mc += __shfl_down(mc, off);
        }
        if (lane == 0) { rp[b][wv] = lp; rr[b][wv] = lr; rm[b][wv] = mc; }
    }
    __syncthreads();
    if (t == 0) {
        float loss = 0.f;
        for (int b = 0; b < 4; ++b) {
            float sp = 0.f, sr = 0.f, sm = 0.f;
            for (int i = 0; i < 8; ++i) { sp += rp[b][i]; sr += rr[b][i]; sm += rm[b][i]; }
            const float denom = fmaxf(sm, 1.f);
            const float lrb = (sp - sr) / denom;
            const float mult = pref[b] ? 1.f : -1.f;
            const float z = 0.1f * (lrb - kl[0]) * mult;
            loss += 1.f / (1.f + __expf(z));   // 1 - sigmoid(z)
        }
        out[0] = loss * 0.25f;
    }
}

extern "C" void kernel_launch(void* const* d_in, const int* in_sizes, int n_in,
                              void* d_out, int out_size, void* d_ws, size_t ws_size,
                              hipStream_t stream) {
    const float* x    = (const float*)d_in[0];
    const float* w0   = (const float*)d_in[1];
    const float* b0   = (const float*)d_in[2];
    const int*   tgt  = (const int*)d_in[3];
    const int*   pref = (const int*)d_in[4];
    const float* xr   = (const float*)d_in[5];
    const float* w1   = (const float*)d_in[6];
    const float* b1   = (const float*)d_in[7];
    const float* kl   = (const float*)d_in[8];
    float* out = (float*)d_out;

    // ws layout: xbf | partials | tgtlog | logp | [wbf if it fits]
    const size_t xbf_b  = (size_t)2 * BT * HD * 2;          // 33.55 MB
    const size_t part_b = (size_t)2 * BT * NCHUNK * 2 * 4;  // 16.38 MB
    const size_t tl_b   = (size_t)2 * BT * 4;
    const size_t wbf_b  = (size_t)2 * VD * HD * 2;          // 524.3 MB

    char* wp = (char*)d_ws;
    uint16_t* xbf     = (uint16_t*)wp;                 wp += xbf_b;
    float*    partials = (float*)wp;                   wp += part_b;
    float*    tgtlog   = (float*)wp;                   wp += tl_b;
    float*    logp     = (float*)wp;                   wp += tl_b;
    uint16_t* wbf      = (uint16_t*)wp;
    const bool use_wbf = ws_size >= (xbf_b + part_b + 2 * tl_b + wbf_b);

    hipLaunchKernelGGL(convert_x, dim3(1024), dim3(256), 0, stream, x, xr, xbf);
    if (use_wbf) {
        hipLaunchKernelGGL(convert_w, dim3(4096), dim3(256), 0, stream, w0, w1, wbf);
        hipLaunchKernelGGL(gemm_lse_bf, dim3(NWG2), dim3(512), 0, stream,
                           xbf, wbf, b0, b1, tgt, partials, tgtlog);
    } else {
        hipLaunchKernelGGL(gemm_lse_f32, dim3(8000), dim3(256), 0, stream,
                           xbf, w0, b0, w1, b1, tgt, partials, tgtlog);
    }
    hipLaunchKernelGGL(lse_reduce, dim3(2 * BT / 4), dim3(256), 0, stream,
                       partials, tgtlog, logp);
    hipLaunchKernelGGL(final_loss, dim3(1), dim3(512), 0, stream, logp, tgt, pref, kl, out);
}

// Round 12
// 1458.033 us; speedup vs baseline: 1.2895x; 1.0170x over previous
//
#include <hip/hip_runtime.h>
#include <hip/hip_bf16.h>
#include <stdint.h>

#define HD 4096
#define VD 32000
#define BT 2048        // B*T rows
#define TT 512
#define IGNORE_IDX (-100)

// bf16 8-wave main GEMM geometry: 256x128 block, BKT=32, wave-tile 64x64
#define BM 256
#define BN 128
#define BKT 32
#define KT (HD / BKT)          // 128 K-tiles
#define NB (VD / BN)           // 250
#define MB (BT / BM)           // 8
#define NWG2 (MB * NB * 2)     // 4000

// partials granularity: 64 columns per chunk (wave-owned) — shared with fallback
#define NCHUNK (VD / 64)       // 500

typedef __attribute__((ext_vector_type(8))) short short8;
typedef __attribute__((ext_vector_type(4))) float f32x4;

__device__ __forceinline__ uint16_t f2bf(float f) {
    uint32_t u = __float_as_uint(f);
    u += 0x7FFFu + ((u >> 16) & 1u);   // round-to-nearest-even
    return (uint16_t)(u >> 16);
}

__device__ __forceinline__ void gload16(const void* g, void* l) {
    __builtin_amdgcn_global_load_lds(
        (const __attribute__((address_space(1))) void*)g,
        (__attribute__((address_space(3))) void*)l, 16, 0, 0);
}

// ---------------- kernel 0a: convert x inputs f32 -> bf16 ----------------
__global__ void convert_x(const float* __restrict__ x0, const float* __restrict__ x1,
                          uint16_t* __restrict__ xbf) {
    const int64_t n4 = (int64_t)BT * HD / 4;
    ushort4* o0 = (ushort4*)xbf;
    ushort4* o1 = (ushort4*)(xbf + (int64_t)BT * HD);
    for (int64_t i = blockIdx.x * (int64_t)blockDim.x + threadIdx.x; i < n4;
         i += (int64_t)gridDim.x * blockDim.x) {
        float4 a = ((const float4*)x0)[i];
        float4 b = ((const float4*)x1)[i];
        ushort4 ua, ub;
        ua.x = f2bf(a.x); ua.y = f2bf(a.y); ua.z = f2bf(a.z); ua.w = f2bf(a.w);
        ub.x = f2bf(b.x); ub.y = f2bf(b.y); ub.z = f2bf(b.z); ub.w = f2bf(b.w);
        o0[i] = ua;
        o1[i] = ub;
    }
}

// ---------------- kernel 0b: convert weights f32 -> bf16 ----------------
__global__ void convert_w(const float* __restrict__ w0, const float* __restrict__ w1,
                          uint16_t* __restrict__ wbf) {
    const int64_t n4 = (int64_t)VD * HD / 4;
    ushort4* o0 = (ushort4*)wbf;
    ushort4* o1 = (ushort4*)(wbf + (int64_t)VD * HD);
    for (int64_t i = blockIdx.x * (int64_t)blockDim.x + threadIdx.x; i < n4;
         i += (int64_t)gridDim.x * blockDim.x) {
        float4 a = ((const float4*)w0)[i];
        float4 b = ((const float4*)w1)[i];
        ushort4 ua, ub;
        ua.x = f2bf(a.x); ua.y = f2bf(a.y); ua.z = f2bf(a.z); ua.w = f2bf(a.w);
        ub.x = f2bf(b.x); ub.y = f2bf(b.y); ub.z = f2bf(b.z); ub.w = f2bf(b.w);
        o0[i] = ua;
        o1[i] = ub;
    }
}

// ---------------- main GEMM tile body (BKT=32): 3 gloads | 8 ds_read | 16 MFMA | join ----
// 64B LDS rows; swizzle: stored slot s at row r holds global slot s ^ ((r%16)>>1 & 3).
template<int CUR>
__device__ __forceinline__ void tile_body(
    int t,
    const uint16_t* __restrict__ agp, const uint16_t* __restrict__ bgp,
    char* aLdst, char* bLdst,
    const char* pA, const char* pB,
    f32x4 (&acc)[4][4])
{
    constexpr int CA  = CUR * 16384;          // A buffer byte offset
    constexpr int CBf = CUR * 8192;           // B buffer byte offset
    constexpr int NXA = (CUR ^ 1) * 16384;
    constexpr int NXB = (CUR ^ 1) * 8192;
    const bool more = (t + 1) < KT;
    const int ko = (t + 1) * BKT;

    if (more) {
        gload16(bgp + ko, bLdst + NXB);                           // B: 1 chunk (16 rows)
        gload16(agp + ko, aLdst + NXA);                           // A chunk 0 (16 rows)
        gload16(agp + (size_t)16 * HD + ko, aLdst + NXA + 1024);  // A chunk 1
    }

    short8 bf[4], af[4];
#pragma unroll
    for (int ni = 0; ni < 4; ++ni)
        bf[ni] = *(const short8*)(pB + ni * 1024 + CBf);
#pragma unroll
    for (int mi = 0; mi < 4; ++mi)
        af[mi] = *(const short8*)(pA + mi * 1024 + CA);
#pragma unroll
    for (int mi = 0; mi < 4; ++mi)
#pragma unroll
        for (int ni = 0; ni < 4; ++ni)
            acc[mi][ni] = __builtin_amdgcn_mfma_f32_16x16x32_bf16(
                af[mi], bf[ni], acc[mi][ni], 0, 0, 0);

    asm volatile("s_waitcnt vmcnt(0)" ::: "memory");
    __builtin_amdgcn_s_barrier();
}

// ---------------- kernel 1 (main): 256x128 GEMM + LSE partials, 2 blocks/CU ----------------
__global__ __launch_bounds__(512, 4) void gemm_lse_bf(
    const uint16_t* __restrict__ xbf, const uint16_t* __restrict__ wbf,
    const float* __restrict__ b0, const float* __restrict__ b1,
    const int* __restrict__ target,
    float* __restrict__ partials, float* __restrict__ tgtlog)
{
    __shared__ uint16_t As[2 * BM * BKT];  // 32 KB (2 buffers of 16 KB)
    __shared__ uint16_t Bs[2 * BN * BKT];  // 16 KB (2 buffers of 8 KB)

    const int orig = blockIdx.x;
    const int wgid = (orig & 7) * (NWG2 / 8) + (orig >> 3);
    const int mb    = wgid & 7;
    const int rest  = wgid >> 3;           // 0..499
    const int nb    = rest % NB;
    const int model = rest / NB;

    const uint16_t* xb = xbf + (size_t)model * BT * HD;
    const uint16_t* wb = wbf + (size_t)model * VD * HD;
    const float* bias  = model ? b1 : b0;

    const int row0 = mb * BM;
    const int c0   = nb * BN;

    const int tid    = threadIdx.x;
    const int lane   = tid & 63;
    const int wid    = tid >> 6;       // 0..7
    const int wr     = wid >> 1;       // 0..3  (M quarter: 64 rows)
    const int wc     = wid & 1;        // 0..1  (N half: 64 cols)

    const int lane15 = lane & 15;
    const int kg     = lane >> 4;      // 0..3 (k-slot of 8 elems)

    // staging: 64B rows, 1KB chunk = 16 rows; lane l -> row l>>2, stored slot l&3,
    // global source slot = (l&3) ^ ((l>>3)&3)   [key = ((row%16)>>1)&3]
    const int srow  = lane >> 2;               // 0..15
    const int gslot = (lane & 3) ^ ((lane >> 3) & 3);
    const uint16_t* agp = xb + (size_t)(row0 + wid * 32 + srow) * HD + gslot * 8;
    const uint16_t* bgp = wb + (size_t)(c0 + wid * 16 + srow) * HD + gslot * 8;
    char* aLdst = (char*)As + wid * 2048;      // 2 chunks per wave (+1024)
    char* bLdst = (char*)Bs + wid * 1024;      // 1 chunk per wave

    // fragment read bases: row*64 + ((kg ^ ((lane15>>1)&3))<<4); per-mi/ni +1024 (16 rows)
    const int rswz = ((kg ^ ((lane15 >> 1) & 3)) << 4);
    const char* pA = (const char*)As + (wr * 64 + lane15) * 64 + rswz;
    const char* pB = (const char*)Bs + (wc * 64 + lane15) * 64 + rswz;

    f32x4 acc[4][4];
#pragma unroll
    for (int i = 0; i < 4; ++i)
#pragma unroll
        for (int j = 0; j < 4; ++j) acc[i][j] = (f32x4){0.f, 0.f, 0.f, 0.f};

    // prologue: stage tile 0 into buf 0, drain, barrier
    gload16(bgp, bLdst);
    gload16(agp, aLdst);
    gload16(agp + (size_t)16 * HD, aLdst + 1024);
    asm volatile("s_waitcnt vmcnt(0)" ::: "memory");
    __builtin_amdgcn_s_barrier();

    for (int t2 = 0; t2 < KT; t2 += 2) {
        tile_body<0>(t2,     agp, bgp, aLdst, bLdst, pA, pB, acc);
        tile_body<1>(t2 + 1, agp, bgp, aLdst, bLdst, pA, pB, acc);
    }

    // ---- epilogue: bias, per-row max/sumexp over this wave's 64 cols ----
    float bv4[4];
#pragma unroll
    for (int ni = 0; ni < 4; ++ni) bv4[ni] = bias[c0 + wc * 64 + ni * 16 + lane15];

#pragma unroll
    for (int mi = 0; mi < 4; ++mi) {
        const int grow_base = row0 + wr * 64 + mi * 16 + kg * 4;
#pragma unroll
        for (int j = 0; j < 4; ++j) {
            const int grow = grow_base + j;
            float v[4];
#pragma unroll
            for (int ni = 0; ni < 4; ++ni) v[ni] = acc[mi][ni][j] + bv4[ni];
            float m = fmaxf(fmaxf(v[0], v[1]), fmaxf(v[2], v[3]));
#pragma unroll
            for (int msk = 1; msk < 16; msk <<= 1)
                m = fmaxf(m, __shfl_xor(m, msk));
            float s = __expf(v[0] - m) + __expf(v[1] - m) +
                      __expf(v[2] - m) + __expf(v[3] - m);
#pragma unroll
            for (int msk = 1; msk < 16; msk <<= 1)
                s += __shfl_xor(s, msk);
            const int tg = target[grow];
#pragma unroll
            for (int ni = 0; ni < 4; ++ni) {
                const int gcol = c0 + wc * 64 + ni * 16 + lane15;
                if (tg == gcol) tgtlog[model * BT + grow] = v[ni];
            }
            if (lane15 == 0) {
                const size_t po = ((size_t)(model * BT + grow) * NCHUNK + nb * 2 + wc) * 2;
                partials[po]     = m;
                partials[po + 1] = s;
            }
        }
    }
}

// ---------------- kernel 1 (fallback, f32 weights): R1 structure ----------------
__global__ __launch_bounds__(256) void gemm_lse_f32(
    const uint16_t* __restrict__ xbf,
    const float* __restrict__ w0, const float* __restrict__ b0,
    const float* __restrict__ w1, const float* __restrict__ b1,
    const int* __restrict__ target,
    float* __restrict__ partials, float* __restrict__ tgtlog)
{
    const int orig = blockIdx.x;               // grid 8000
    const int wgid = (orig & 7) * 1000 + (orig >> 3);
    const int mb    = wgid & 7;
    const int rest  = wgid >> 3;
    const int chunk = rest % 500;
    const int model = rest / 500;

    const float* w    = model ? w1 : w0;
    const float* bias = model ? b1 : b0;
    const uint16_t* xb = xbf + (size_t)model * BT * HD;

    const int row0 = mb * 256;
    const int c0   = chunk * 64;

    const int tid  = threadIdx.x;
    const int lane = tid & 63;
    const int wid  = tid >> 6;

    __shared__ uint16_t As_[256 * 64];
    __shared__ uint16_t Bs_[64 * 64];

    f32x4 acc[4][4];
#pragma unroll
    for (int i = 0; i < 4; ++i)
#pragma unroll
        for (int j = 0; j < 4; ++j) acc[i][j] = (f32x4){0.f, 0.f, 0.f, 0.f};

    const int srow8 = lane >> 3;
    const int slot  = (lane & 7) ^ srow8;
    const uint16_t* agsrc = xb + (size_t)(row0 + wid * 64 + srow8) * HD + slot * 8;
    char* aldst = (char*)As_ + wid * 8192;

    const int ss   = tid & 7;
    const int srow = tid >> 3;
    const int swz_w = (srow & 7) << 4;
    const float* bptr = w + (size_t)(c0 + srow) * HD + ss * 8;

    const int lane15 = lane & 15;
    const int kg     = lane >> 4;
    const int swz_r  = (lane & 7) << 4;

    for (int kt = 0; kt < 64; ++kt) {
        const int kofs = kt * 64;
#pragma unroll
        for (int c = 0; c < 8; ++c)
            gload16(agsrc + (size_t)c * 8 * HD + kofs, aldst + c * 1024);
        {
            float4 bv[2][2];
#pragma unroll
            for (int r = 0; r < 2; ++r) {
                const float* p = bptr + (size_t)r * 32 * HD + kofs;
                bv[r][0] = *(const float4*)(p);
                bv[r][1] = *(const float4*)(p + 4);
            }
#pragma unroll
            for (int r = 0; r < 2; ++r) {
                const int row_l = srow + r * 32;
                float fv[8] = {bv[r][0].x, bv[r][0].y, bv[r][0].z, bv[r][0].w,
                               bv[r][1].x, bv[r][1].y, bv[r][1].z, bv[r][1].w};
                uint32_t pk[4];
#pragma unroll
                for (int e = 0; e < 4; ++e)
                    pk[e] = (uint32_t)f2bf(fv[2 * e]) | ((uint32_t)f2bf(fv[2 * e + 1]) << 16);
                const int off = (row_l * 128 + ss * 16) ^ swz_w;
                *(uint4*)((char*)Bs_ + off) = *(uint4*)pk;
            }
        }
        __syncthreads();
#pragma unroll
        for (int ks = 0; ks < 2; ++ks) {
            short8 af[4], bf[4];
#pragma unroll
            for (int mi = 0; mi < 4; ++mi) {
                const int arow = wid * 64 + mi * 16 + lane15;
                const int off = (arow * 128 + ks * 64 + kg * 16) ^ swz_r;
                af[mi] = *(const short8*)((const char*)As_ + off);
            }
#pragma unroll
            for (int ni = 0; ni < 4; ++ni) {
                const int brow = ni * 16 + lane15;
                const int off = (brow * 128 + ks * 64 + kg * 16) ^ swz_r;
                bf[ni] = *(const short8*)((const char*)Bs_ + off);
            }
#pragma unroll
            for (int mi = 0; mi < 4; ++mi)
#pragma unroll
                for (int ni = 0; ni < 4; ++ni)
                    acc[mi][ni] = __builtin_amdgcn_mfma_f32_16x16x32_bf16(
                        af[mi], bf[ni], acc[mi][ni], 0, 0, 0);
        }
        __syncthreads();
    }

    float bv4[4];
#pragma unroll
    for (int ni = 0; ni < 4; ++ni) bv4[ni] = bias[c0 + ni * 16 + lane15];

#pragma unroll
    for (int mi = 0; mi < 4; ++mi) {
        const int grow_base = row0 + wid * 64 + mi * 16 + kg * 4;
#pragma unroll
        for (int j = 0; j < 4; ++j) {
            const int grow = grow_base + j;
            float v[4];
#pragma unroll
            for (int ni = 0; ni < 4; ++ni) v[ni] = acc[mi][ni][j] + bv4[ni];
            float m = fmaxf(fmaxf(v[0], v[1]), fmaxf(v[2], v[3]));
#pragma unroll
            for (int msk = 1; msk < 16; msk <<= 1)
                m = fmaxf(m, __shfl_xor(m, msk));
            float s = __expf(v[0] - m) + __expf(v[1] - m) +
                      __expf(v[2] - m) + __expf(v[3] - m);
#pragma unroll
            for (int msk = 1; msk < 16; msk <<= 1)
                s += __shfl_xor(s, msk);
            const int tg = target[grow];
#pragma unroll
            for (int ni = 0; ni < 4; ++ni) {
                const int gcol = c0 + ni * 16 + lane15;
                if (tg == gcol) tgtlog[model * BT + grow] = v[ni];
            }
            if (lane15 == 0) {
                const size_t po = ((size_t)(model * BT + grow) * NCHUNK + chunk) * 2;
                partials[po]     = m;
                partials[po + 1] = s;
            }
        }
    }
}

// ---------------- kernel 2: combine chunk partials -> lse -> per-token logp ----------------
__global__ void lse_reduce(const float* __restrict__ partials,
                           const float* __restrict__ tgtlog,
                           float* __restrict__ logp) {
    const int gw = blockIdx.x * (blockDim.x >> 6) + (threadIdx.x >> 6);
    if (gw >= 2 * BT) return;
    const int lane = threadIdx.x & 63;
    const float* p = partials + (size_t)gw * NCHUNK * 2;

    float m = -1e30f;
#pragma unroll
    for (int i = 0; i < 8; ++i) {
        const int c = lane + i * 64;
        if (c < NCHUNK) m = fmaxf(m, p[c * 2]);
    }
#pragma unroll
    for (int msk = 1; msk < 64; msk <<= 1) m = fmaxf(m, __shfl_xor(m, msk));
    float s = 0.f;
#pragma unroll
    for (int i = 0; i < 8; ++i) {
        const int c = lane + i * 64;
        if (c < NCHUNK) s += p[c * 2 + 1] * __expf(p[c * 2] - m);
    }
#pragma unroll
    for (int msk = 1; msk < 64; msk <<= 1) s += __shfl_xor(s, msk);
    if (lane == 0) {
        const float lse = m + __logf(s);
        logp[gw] = tgtlog[gw] - lse;
    }
}

// ---------------- kernel 3: KTO loss ----------------
__global__ void final_loss(const float* __restrict__ logp, const int* __restrict__ target,
                           const int* __restrict__ pref, const float* __restrict__ kl,
                           float* __restrict__ out) {
    const int t = threadIdx.x;          // 512 threads
    const int lane = t & 63, wv = t >> 6;
    __shared__ float rp[4][8], rr[4][8], rm[4][8];
#pragma unroll
    for (int b = 0; b < 4; ++b) {
        const int idx = b * TT + t;
        const int tg = target[idx];
        const bool mk = (tg != IGNORE_IDX);
        float lp = mk ? logp[idx] : 0.f;
        float lr = mk ? logp[BT + idx] : 0.f;
        float mc = mk ? 1.f : 0.f;
        for (int off = 32; off; off >>= 1) {
            lp += __shfl_down(lp, off);
            lr += __shfl_down(lr, off);
            mc += __shfl_down(mc, off);
        }
        if (lane == 0) { rp[b][wv] = lp; rr[b][wv] = lr; rm[b][wv] = mc; }
    }
    __syncthreads();
    if (t == 0) {
        float loss = 0.f;
        for (int b = 0; b < 4; ++b) {
            float sp = 0.f, sr = 0.f, sm = 0.f;
            for (int i = 0; i < 8; ++i) { sp += rp[b][i]; sr += rr[b][i]; sm += rm[b][i]; }
            const float denom = fmaxf(sm, 1.f);
            const float lrb = (sp - sr) / denom;
            const float mult = pref[b] ? 1.f : -1.f;
            const float z = 0.1f * (lrb - kl[0]) * mult;
            loss += 1.f / (1.f + __expf(z));   // 1 - sigmoid(z)
        }
        out[0] = loss * 0.25f;
    }
}

extern "C" void kernel_launch(void* const* d_in, const int* in_sizes, int n_in,
                              void* d_out, int out_size, void* d_ws, size_t ws_size,
                              hipStream_t stream) {
    const float* x    = (const float*)d_in[0];
    const float* w0   = (const float*)d_in[1];
    const float* b0   = (const float*)d_in[2];
    const int*   tgt  = (const int*)d_in[3];
    const int*   pref = (const int*)d_in[4];
    const float* xr   = (const float*)d_in[5];
    const float* w1   = (const float*)d_in[6];
    const float* b1   = (const float*)d_in[7];
    const float* kl   = (const float*)d_in[8];
    float* out = (float*)d_out;

    // ws layout: xbf | partials | tgtlog | logp | [wbf if it fits]
    const size_t xbf_b  = (size_t)2 * BT * HD * 2;          // 33.55 MB
    const size_t part_b = (size_t)2 * BT * NCHUNK * 2 * 4;  // 16.38 MB
    const size_t tl_b   = (size_t)2 * BT * 4;
    const size_t wbf_b  = (size_t)2 * VD * HD * 2;          // 524.3 MB

    char* wp = (char*)d_ws;
    uint16_t* xbf     = (uint16_t*)wp;                 wp += xbf_b;
    float*    partials = (float*)wp;                   wp += part_b;
    float*    tgtlog   = (float*)wp;                   wp += tl_b;
    float*    logp     = (float*)wp;                   wp += tl_b;
    uint16_t* wbf      = (uint16_t*)wp;
    const bool use_wbf = ws_size >= (xbf_b + part_b + 2 * tl_b + wbf_b);

    hipLaunchKernelGGL(convert_x, dim3(1024), dim3(256), 0, stream, x, xr, xbf);
    if (use_wbf) {
        hipLaunchKernelGGL(convert_w, dim3(4096), dim3(256), 0, stream, w0, w1, wbf);
        hipLaunchKernelGGL(gemm_lse_bf, dim3(NWG2), dim3(512), 0, stream,
                           xbf, wbf, b0, b1, tgt, partials, tgtlog);
    } else {
        hipLaunchKernelGGL(gemm_lse_f32, dim3(8000), dim3(256), 0, stream,
                           xbf, w0, b0, w1, b1, tgt, partials, tgtlog);
    }
    hipLaunchKernelGGL(lse_reduce, dim3(2 * BT / 4), dim3(256), 0, stream,
                       partials, tgtlog, logp);
    hipLaunchKernelGGL(final_loss, dim3(1), dim3(512), 0, stream, logp, tgt, pref, kl, out);
}